// Round 7
// baseline (263.376 us; speedup 1.0000x reference)
//
#include <hip/hip_runtime.h>
#include <cstdint>
#include <cstddef>

typedef int int32x4  __attribute__((ext_vector_type(4)));
typedef int int32x16 __attribute__((ext_vector_type(16)));

#define AS1 __attribute__((address_space(1)))
#define AS3 __attribute__((address_space(3)))

__device__ __forceinline__ void gload_lds16(const void* g, void* l) {
    __builtin_amdgcn_global_load_lds((const AS1 void*)g, (AS3 void*)l, 16, 0, 0);
}

// ---------------------------------------------------------------------------
// Kernel 1: x (fp32, int8-valued) -> A8 (int8, row-major) + row sums rs.
// ---------------------------------------------------------------------------
__global__ __launch_bounds__(256) void quant_x(const float* __restrict__ x,
                                               signed char* __restrict__ A8,
                                               int* __restrict__ rs) {
    const int row = blockIdx.x;
    const int t = threadIdx.x;
    const float4* xr = (const float4*)(x + (size_t)row * 4096);
    char4* ar = (char4*)(A8 + (size_t)row * 4096);
    int s = 0;
#pragma unroll
    for (int i = 0; i < 4; i++) {
        const int idx = i * 256 + t;
        float4 v = xr[idx];
        int a0 = (int)v.x, a1 = (int)v.y, a2 = (int)v.z, a3 = (int)v.w;
        s += a0 + a1 + a2 + a3;
        char4 c;
        c.x = (signed char)a0; c.y = (signed char)a1;
        c.z = (signed char)a2; c.w = (signed char)a3;
        ar[idx] = c;
    }
#pragma unroll
    for (int off = 32; off > 0; off >>= 1) s += __shfl_down(s, off);
    __shared__ int wsum[4];
    if ((t & 63) == 0) wsum[t >> 6] = s;
    __syncthreads();
    if (t == 0) rs[row] = wsum[0] + wsum[1] + wsum[2] + wsum[3];
}

// ---------------------------------------------------------------------------
// Kernel 2: y (fp32, uint8-valued) -> Bpk: MFMA-FRAGMENT-LINEAR packed int8
// (y-128), + col sums sy (fused; sy pre-zeroed by memset).
// Pack: element (n,k) -> chunk (n>>5, k>>5), lane = (n&31) + 32*((k>>4)&1),
// byte k&15.  offset = ((n>>5)*128 + (k>>5))*1024 + lane*16 + (k&15).
// A 64-lane fragment load (lane*16) then yields exactly the bytes the
// 32x32x32 i8 MFMA B-operand wants (identical mapping to the B8T ds_read
// pattern validated in rounds 1-6, absmax 32).
// Block: 64k x 64n tile, LDS byte-transpose (pitch 68), stores fully
// coalesced (consecutive t -> consecutive 16B in packed layout).
// ---------------------------------------------------------------------------
__global__ __launch_bounds__(256) void quant_y(const float* __restrict__ y,
                                               signed char* __restrict__ Bpk,
                                               int* __restrict__ sy) {
    __shared__ __align__(16) signed char tile[64 * 68];  // tile[n*68 + k]
    __shared__ int ssum[64];
    const int nt = blockIdx.x * 64;
    const int kt = blockIdx.y * 64;
    const int t = threadIdx.x;
    if (t < 64) ssum[t] = 0;
    __syncthreads();

    const int r0 = t >> 4;         // k-offset within tile group
    const int c4 = (t & 15) * 4;   // n-offset (4 cols per thread)
    int s0 = 0, s1 = 0, s2 = 0, s3 = 0;
#pragma unroll
    for (int i = 0; i < 4; i++) {
        const int k = i * 16 + r0;
        float4 v = *(const float4*)(y + (size_t)(kt + k) * 4096 + nt + c4);
        int b0 = (int)v.x - 128, b1 = (int)v.y - 128;
        int b2 = (int)v.z - 128, b3 = (int)v.w - 128;
        s0 += b0; s1 += b1; s2 += b2; s3 += b3;
        tile[(c4 + 0) * 68 + k] = (signed char)b0;
        tile[(c4 + 1) * 68 + k] = (signed char)b1;
        tile[(c4 + 2) * 68 + k] = (signed char)b2;
        tile[(c4 + 3) * 68 + k] = (signed char)b3;
    }
    atomicAdd(&ssum[c4 + 0], s0);
    atomicAdd(&ssum[c4 + 1], s1);
    atomicAdd(&ssum[c4 + 2], s2);
    atomicAdd(&ssum[c4 + 3], s3);
    __syncthreads();

    // Store phase: thread t -> one 16B granule of the packed layout.
    const int q  = t & 127;        // granule within 2KB (n-half) region
    const int rh = t >> 7;         // n-half of tile (0/1)
    const int k32sel = q >> 6;     // which k32 chunk
    const int lq = q & 63;         // lane index within chunk
    const int n_loc = rh * 32 + (lq & 31);
    const int k_loc = k32sel * 32 + (lq >> 5) * 16;
    const signed char* src = tile + n_loc * 68 + k_loc;
    int32x4 w;
    w.x = *(const int*)(src + 0);
    w.y = *(const int*)(src + 4);
    w.z = *(const int*)(src + 8);
    w.w = *(const int*)(src + 12);
    const size_t dst = ((size_t)((nt >> 5) + rh) * 128 + (kt >> 5) + k32sel) * 1024 + lq * 16;
    *(int32x4*)(Bpk + dst) = w;
    if (t < 64) atomicAdd(&sy[nt + t], ssum[t]);
}

// ---------------------------------------------------------------------------
// Kernel 3: int8 GEMM, ZERO barriers (AITER/flatmm-style decoupled waves).
// Block 256x128 = 4 independent waves (2x2), wave tile 128x64, BK=64,
// 16 v_mfma_i32_32x32x32_i8 per wave-iter.
//  - A: per-wave PRIVATE LDS staging (2 bufs x 8KB per wave, 64KB/block)
//    via global_load_lds; wave gates ONLY on its own vmcnt -> no s_barrier.
//  - B: fragment-linear packed in DRAM (Bpk), loaded global->VGPR with
//    1KB lane-linear loads, register double-buffered; compiler's precise
//    vmcnt guards the reg deps.
//  - Manual s_waitcnt vmcnt(12): allow newest 12 (B(i+1)4 + A(i+2)8 wait...
//    precisely: newest-12 = current iter's B-loads + stage; everything older
//    (incl. A(i), B(i)) complete. sched_barrier(0) fences keep ds_reads
//    after the wait and before the same-buffer re-stage (DMA lands >=200cyc
//    after issue; ds_reads execute at issue -> no overwrite race).
//  - Clamped (&4095) tail staging keeps vmcnt counts constant every iter.
// LDS layout: dense 64B rows + XOR chunk swizzle slot = chunk ^ ((row>>1)&3).
// Epilogue: C = 7.5e-4 * (P - 32*rs[m] + 66*sy[n] - 8650752)
// ---------------------------------------------------------------------------
__global__ __launch_bounds__(256, 2) void gemm_i8(const signed char* __restrict__ A8,
                                                  const signed char* __restrict__ Bpk,
                                                  const int* __restrict__ rs,
                                                  const int* __restrict__ sy,
                                                  float* __restrict__ C) {
    __shared__ __align__(16) signed char As[4][2][8192];  // [wave][buf] 64 KB
    const int tid = threadIdx.x;
    const int bm = blockIdx.y * 256;
    const int bn = blockIdx.x * 128;
    const int lane = tid & 63;
    const int wave = tid >> 6;
    const int wm = (wave >> 1) * 128;
    const int wn = (wave & 1) * 64;
    const int mr = lane & 31;
    const int kh = lane >> 5;

    int32x16 acc[4][2] = {};

    // A staging (per wave): instr p covers rows p*16..p*16+15 of the wave's
    // 128-row band; lane -> row p*16 + (lane>>2) (adjacent quads), source
    // chunk (lane&3)^((lane>>3)&3) lands at phys slot lane&3 (XOR swizzle).
    const int srow = lane >> 2;
    const int scol = ((lane & 3) ^ ((lane >> 3) & 3)) * 16;
    const signed char* a_src = A8 + (size_t)(bm + wm + srow) * 4096 + scol;
    signed char* a_lds = &As[wave][0][0] + lane * 16;

    // fragment LDS offsets (relative to buf base)
    int aoff[4][2];
#pragma unroll
    for (int ks = 0; ks < 2; ks++)
#pragma unroll
        for (int i = 0; i < 4; i++)
            aoff[i][ks] = (i * 32 + mr) * 64 + (((ks * 2 + kh)) ^ ((mr >> 1) & 3)) * 16;

    // B packed base for this wave's two n32 chunks
    const signed char* b_base = Bpk + ((size_t)((bn + wn) >> 5) * 128) * 1024 + lane * 16;

    auto stageA = [&](int buf, int kt) {
        const signed char* s = a_src + kt;
        signed char* d = a_lds + buf * 8192;
#pragma unroll
        for (int p = 0; p < 8; p++)
            gload_lds16(s + (size_t)p * (16 * 4096), d + p * 1024);
    };
    auto loadB = [&](int32x4 (&bf)[2][2], int kt) {
        const int k32 = kt >> 5;
#pragma unroll
        for (int nj = 0; nj < 2; nj++)
#pragma unroll
            for (int ks = 0; ks < 2; ks++)
                bf[nj][ks] = *(const int32x4*)(b_base + ((size_t)nj * 128 + k32 + ks) * 1024);
    };

    int32x4 bcur[2][2], bnxt[2][2];
    stageA(0, 0);        // A(0)
    loadB(bcur, 0);      // B(0)
    stageA(1, 64);       // A(1)

#pragma unroll 1
    for (int kt = 0; kt < 4096; kt += 64) {
        const int i = kt >> 6;
        loadB(bnxt, (kt + 64) & 4095);               // B(i+1)
        __builtin_amdgcn_s_waitcnt(0xF7C);           // vmcnt(12): A(i),B(i) done
        __builtin_amdgcn_sched_barrier(0);
        int32x4 af[4][2];
        const signed char* Ab = &As[wave][i & 1][0];
#pragma unroll
        for (int ks = 0; ks < 2; ks++)
#pragma unroll
            for (int m = 0; m < 4; m++)
                af[m][ks] = *(const int32x4*)(Ab + aoff[m][ks]);
        __builtin_amdgcn_sched_barrier(0);
        stageA(i & 1, (kt + 128) & 4095);            // A(i+2) into just-read buf
#pragma unroll
        for (int ks = 0; ks < 2; ks++)
#pragma unroll
            for (int m = 0; m < 4; m++)
#pragma unroll
                for (int nj = 0; nj < 2; nj++)
                    acc[m][nj] = __builtin_amdgcn_mfma_i32_32x32x32_i8(af[m][ks], bcur[nj][ks], acc[m][nj], 0, 0, 0);
#pragma unroll
        for (int nj = 0; nj < 2; nj++)
#pragma unroll
            for (int ks = 0; ks < 2; ks++)
                bcur[nj][ks] = bnxt[nj][ks];
    }

    // Epilogue. C/D: col = lane&31, row = (reg&3) + 8*(reg>>2) + 4*kh
#pragma unroll
    for (int i = 0; i < 4; i++) {
#pragma unroll
        for (int r = 0; r < 16; r++) {
            const int gm = bm + wm + i * 32 + (r & 3) + 8 * (r >> 2) + 4 * kh;
            const int rcorr = -32 * rs[gm] - 8650752;
#pragma unroll
            for (int j = 0; j < 2; j++) {
                const int gn = bn + wn + j * 32 + mr;
                const int v = acc[i][j][r] + rcorr + 66 * sy[gn];
                C[(size_t)gm * 4096 + gn] = 7.5e-4f * (float)v;
            }
        }
    }
}

// ---------------------------------------------------------------------------
extern "C" void kernel_launch(void* const* d_in, const int* in_sizes, int n_in,
                              void* d_out, int out_size, void* d_ws, size_t ws_size,
                              hipStream_t stream) {
    const float* x = (const float*)d_in[0];  // [4096,4096] int8-valued
    const float* y = (const float*)d_in[1];  // [4096,4096] uint8-valued
    float* out = (float*)d_out;

    char* ws = (char*)d_ws;
    signed char* A8  = (signed char*)ws;                         // 16 MiB
    signed char* Bpk = (signed char*)(ws + (16u << 20));         // 16 MiB packed
    int* rs = (int*)(ws + (32u << 20));                          // 16 KiB
    int* sy = (int*)(ws + (32u << 20) + (16u << 10));            // 16 KiB

    hipMemsetAsync(sy, 0, 4096 * sizeof(int), stream);
    quant_x<<<4096, 256, 0, stream>>>(x, A8, rs);
    quant_y<<<dim3(64, 64), 256, 0, stream>>>(y, Bpk, sy);
    gemm_i8<<<dim3(32, 16), 256, 0, stream>>>(A8, Bpk, rs, sy, out);
}